// Round 22
// baseline (170.841 us; speedup 1.0000x reference)
//
#include <hip/hip_runtime.h>
#include <hip/hip_bf16.h>

// TuckER: out[b] = sum_{i,j,k} p[b,i] r[b,j] q[b,k] W[i,j,k]
// Pipeline (6 launches):
//   fused_csr: counts->scan->fill in ONE block (LDS); zeroes norm accum
//   norm:      REG norms (which 0..2) + conv_r fp32->bf16 (which==3)
//   conv_wt:   W[i][j][k] fp32 -> Wt[(i,k)][j] bf16 (transpose)
//   stage1:    WR[r,(i,k)] = sum_j R[r,j] Wt[(ik),j]  MFMA bf16 GEMM.
//              PERSISTENT-STRIP (64 strips x 8 r-blocks, lockstep panels,
//              XCD co-location: Wt/XCD = 4MB = L2). REGISTER-RESIDENT R.
//              DEFERRED-SPREAD STORES: panel output packed to regs at kt3,
//              issued 2/step during the NEXT panel; counted s_waitcnt
//              vmcnt(2) + raw s_barrier per step so stores drain under
//              compute instead of at a vmcnt(0) burst (R16 lesson: stores
//              count toward vmcnt; in-order retirement means vmcnt(0)
//              serializes the 32KB burst). Store count kept wave-uniform
//              by clamping OOB rows to dump row `cnt` (WR has cnt+1 rows).
//              WR layout (bytes): r*131072 + (i>>4)*8192 + (i&15)*512
//                                 + (k>>5)*64 + [granule: g*16 + e*2]
//              where k&31 = (e>>2)*16 + g*4 + (e&3)
//   stage2:    per-bucket MFMA: A = WR frags (streamed), B = q (16 samples)
//   sum_out:   out[b] = partial halves; also writes out[B] (reg term)

#define DDIM 256
#define NIK  65536
#define BM   128
#define BN   128
#define BK   64
#define NCH2 2
#define NPANEL 8

typedef unsigned int uint;
typedef __attribute__((ext_vector_type(8))) short bf16x8;
typedef __attribute__((ext_vector_type(4))) float f32x4;

static __device__ __forceinline__ unsigned short f2bf(float f) {
    __hip_bfloat16 h = __float2bfloat16(f);
    return *reinterpret_cast<unsigned short*>(&h);
}
static __device__ __forceinline__ float bf2f(unsigned short u) {
    return __uint_as_float(((uint)u) << 16);
}

#define GLOAD_LDS16(gsrc, ldst)                                                \
    __builtin_amdgcn_global_load_lds(                                          \
        (const __attribute__((address_space(1))) void*)(gsrc),                 \
        (__attribute__((address_space(3))) void*)(ldst), 16, 0, 0)

// ---------------- fused CSR: prep+hist+scan+fill in one block ---------------
__global__ __launch_bounds__(1024)
void fused_csr_kernel(const int* __restrict__ rs, int* __restrict__ offs,
                      int* __restrict__ list, float* __restrict__ norms,
                      int B, int n) {
    __shared__ int cnt[1024];
    __shared__ int buf[2][1024];
    const int t = threadIdx.x;
    if (t < 3) norms[t] = 0.f;
    cnt[t] = 0;
    __syncthreads();
    for (int b = t; b < B; b += 1024) atomicAdd(&cnt[rs[b]], 1);
    __syncthreads();
    const int myc = cnt[t];
    int cur = 0;
    buf[0][t] = (t < n) ? myc : 0;
    __syncthreads();
    for (int d = 1; d < 1024; d <<= 1) {
        int x = buf[cur][t] + ((t >= d) ? buf[cur][t - d] : 0);
        buf[cur ^ 1][t] = x;
        cur ^= 1;
        __syncthreads();
    }
    if (t < n) {
        int inc = buf[cur][t];
        offs[t + 1] = inc;
        if (t == 0) offs[0] = 0;
        cnt[t] = inc - myc;  // exclusive start -> fill cursor
    }
    __syncthreads();
    for (int b = t; b < B; b += 1024) {
        int pos = atomicAdd(&cnt[rs[b]], 1);
        list[pos] = b;
    }
}

// ---------------- Norms (which 0..2) + conv_r (which==3) --------------------
__global__ __launch_bounds__(256)
void norm_kernel(const int* __restrict__ ps, const int* __restrict__ qs,
                 const int* __restrict__ rs, const float* __restrict__ P,
                 const float* __restrict__ Q, const float* __restrict__ R,
                 unsigned short* __restrict__ Rb, float* __restrict__ accum,
                 int B, int n4) {
    const int which = blockIdx.y;
    if (which == 3) {
        for (int idx = blockIdx.x * 256 + threadIdx.x; idx < n4;
             idx += 128 * 256) {
            float4 v = *reinterpret_cast<const float4*>(R + idx * 4);
            ushort4 o;
            o.x = f2bf(v.x); o.y = f2bf(v.y); o.z = f2bf(v.z); o.w = f2bf(v.w);
            *reinterpret_cast<ushort4*>(Rb + idx * 4) = o;
        }
        return;
    }
    const int*   idx = (which == 0) ? ps : (which == 1) ? qs : rs;
    const float* tab = (which == 0) ? P : (which == 1) ? Q : R;
    float a = 0.f;
    const int total = B * 64;
    for (int e = blockIdx.x * 256 + threadIdx.x; e < total; e += 128 * 256) {
        int b = e >> 6, cc = e & 63;
        float4 v = *reinterpret_cast<const float4*>(tab + (size_t)idx[b] * DDIM + cc * 4);
        a += v.x * v.x + v.y * v.y + v.z * v.z + v.w * v.w;
    }
#pragma unroll
    for (int off = 32; off; off >>= 1) a += __shfl_down(a, off, 64);
    __shared__ float red[4];
    if ((threadIdx.x & 63) == 0) red[threadIdx.x >> 6] = a;
    __syncthreads();
    if (threadIdx.x == 0) atomicAdd(accum + which, red[0] + red[1] + red[2] + red[3]);
}

// ---------------- transpose-convert W: [i][j][k] f32 -> [(i,k)][j] bf16 -----
__global__ __launch_bounds__(256)
void conv_wt_kernel(const float* __restrict__ W, unsigned short* __restrict__ Wt) {
    const int k0 = blockIdx.x * 64;
    const int j0 = blockIdx.y * 128;
    const int i  = blockIdx.z;
    const int t  = threadIdx.x;

    __shared__ float sT[64][129];

    const float* Wi = W + (size_t)i * NIK;
#pragma unroll
    for (int it = 0; it < 8; ++it) {
        int slot = it * 256 + t;
        int jj = slot >> 4, c = slot & 15;
        float4 v = *reinterpret_cast<const float4*>(
            Wi + (size_t)(j0 + jj) * DDIM + k0 + c * 4);
        sT[c * 4 + 0][jj] = v.x;
        sT[c * 4 + 1][jj] = v.y;
        sT[c * 4 + 2][jj] = v.z;
        sT[c * 4 + 3][jj] = v.w;
    }
    __syncthreads();
#pragma unroll
    for (int it = 0; it < 4; ++it) {
        int u = it * 256 + t;
        int kk = u >> 4, jg = u & 15;
        union { unsigned short us[8]; uint4 v; } pk;
#pragma unroll
        for (int m = 0; m < 8; ++m) pk.us[m] = f2bf(sT[kk][jg * 8 + m]);
        *reinterpret_cast<uint4*>(
            Wt + (size_t)(i * DDIM + k0 + kk) * DDIM + j0 + jg * 8) = pk.v;
    }
}

// ---------------- Stage 1: persistent-strip, R in regs, deferred stores -----
__global__ __launch_bounds__(256, 2)
void stage1_kernel(const unsigned short* __restrict__ Rb,
                   const unsigned short* __restrict__ Wt,
                   unsigned short* __restrict__ WR,
                   int r_lo, int cnt) {
    const int t     = threadIdx.x;
    const int lane  = t & 63;
    const int wid   = t >> 6;
    const int strip = blockIdx.x;        // 0..63 ; XCD = strip%8
    const int r0    = blockIdx.y * BM;

    __shared__ char smem[32768];   // [B0|B1] 16KB each (Wt staging only)

    const int wr = (wid >> 1) * 64;
    const int wn = (wid & 1) * 64;

    // ---- load R fragments once: 8 K-slices x 4 row-frags = 32 bf16x8 ------
    bf16x8 rfrag[8][4];
    {
#pragma unroll
        for (int rd = 0; rd < 4; ++rd) {   // K=64 slice rd
            const int j0s = rd * BK;
            __syncthreads();  // buffer free (prev slice's reads done)
#pragma unroll
            for (int c = 0; c < 4; ++c) {
                int u = c * 256 + t;
                int row = u >> 3, g = u & 7;
                int rg = r0 + row;
                if (rg >= cnt) rg = 0;
                GLOAD_LDS16(Rb + (size_t)(r_lo + rg) * DDIM + j0s +
                                ((g ^ (row & 7)) << 3),
                            smem + u * 16);
            }
            __syncthreads();  // staged
#pragma unroll
            for (int ks = 0; ks < 2; ++ks) {
                const int jg = ks * 4 + (lane >> 4);
#pragma unroll
                for (int f = 0; f < 4; ++f) {
                    int rowA = wr + f * 16 + (lane & 15);
                    rfrag[rd * 2 + ks][f] = *reinterpret_cast<const bf16x8*>(
                        smem + rowA * 128 + ((jg ^ (rowA & 7)) << 4));
                }
            }
        }
        __syncthreads();  // all rfrag reads done before B staging reuses smem
    }

    f32x4 acc[4][4];
#pragma unroll
    for (int a = 0; a < 4; ++a)
#pragma unroll
        for (int b = 0; b < 4; ++b) {
            acc[a][b][0] = 0.f; acc[a][b][1] = 0.f;
            acc[a][b][2] = 0.f; acc[a][b][3] = 0.f;
        }

    // stage Wt for (panel p, kt) into buffer offset boff (0 or 16384)
#define STAGE_W(p, kt, boff)                                                    \
    {                                                                           \
        const int j0s = (kt) * BK;                                              \
        const int n0s = strip * (BN * NPANEL) + (p) * BN;                       \
        _Pragma("unroll")                                                       \
        for (int c = 0; c < 4; ++c) {                                           \
            int u = c * 256 + t;                                                \
            int row = u >> 3, g = u & 7;                                        \
            GLOAD_LDS16(Wt + (size_t)(n0s + row) * DDIM + j0s +                 \
                            ((g ^ (row & 7)) << 3),                             \
                        smem + (boff) + u * 16);                                \
        }                                                                       \
    }

    STAGE_W(0, 0, 0);
    asm volatile("s_waitcnt vmcnt(0)" ::: "memory");
    __builtin_amdgcn_sched_barrier(0);
    __builtin_amdgcn_s_barrier();
    __builtin_amdgcn_sched_barrier(0);

    const int c16   = lane & 15;
    const int gq    = lane >> 4;
    const int ubase = wn >> 5;  // 0 or 2
    char* WRb = (char*)WR;

    uint4  pend[8];     // deferred panel output (packed bf16)
    size_t pobase = 0;  // its obase

    for (int p = 0; p < NPANEL; ++p) {
#pragma unroll
        for (int kt = 0; kt < 4; ++kt) {
            const int  coff = (kt & 1) << 14;   // static per unrolled kt
            const bool last = (p == NPANEL - 1) && (kt == 3);

            // L: issue next step's Wt staging (4 DMA loads)
            if (kt < 3) {
                STAGE_W(p, kt + 1, coff ^ 16384);
            } else if (p < NPANEL - 1) {
                STAGE_W(p + 1, 0, coff ^ 16384);
            }

            // S: two deferred stores from previous panel (count-uniform:
            //    OOB rows clamp to dump row `cnt`, never read by stage2)
            if (p > 0) {
                int rg  = r0 + wr + kt * 16 + c16;
                int rgc = rg < cnt ? rg : cnt;
                char* sp = WRb + (size_t)rgc * 131072 + pobase + gq * 16;
                *reinterpret_cast<uint4*>(sp + ubase * 64)       = pend[2 * kt];
                *reinterpret_cast<uint4*>(sp + (ubase + 1) * 64) = pend[2 * kt + 1];
            }

            // C: compute current buffer
            char* Bcur = smem + coff;
#pragma unroll
            for (int ks = 0; ks < 2; ++ks) {
                bf16x8 a[4];
                const int jg = ks * 4 + (lane >> 4);
#pragma unroll
                for (int f = 0; f < 4; ++f) {
                    int rowB = wn + f * 16 + (lane & 15);
                    a[f] = *reinterpret_cast<const bf16x8*>(
                        Bcur + rowB * 128 + ((jg ^ (rowB & 7)) << 4));
                }
#pragma unroll
                for (int fi = 0; fi < 4; ++fi)
#pragma unroll
                    for (int fr = 0; fr < 4; ++fr)
                        acc[fi][fr] = __builtin_amdgcn_mfma_f32_16x16x32_bf16(
                            a[fi], rfrag[kt * 2 + ks][fr], acc[fi][fr],
                            0, 0, 0);
            }

            if (kt == 3) {
                // pack panel output into pend regs; defer stores to next panel
                const int n0  = strip * (BN * NPANEL) + p * BN;
                const int i_g = n0 >> 8;
                pobase = (size_t)(i_g >> 4) * 8192 +
                         (size_t)(i_g & 15) * 512 +
                         (size_t)(n0 & 255) * 2;
#pragma unroll
                for (int fr = 0; fr < 4; ++fr) {
#pragma unroll
                    for (int kts = 0; kts < 2; ++kts) {
                        union { unsigned short us[8]; uint4 v; } pk;
#pragma unroll
                        for (int vv = 0; vv < 4; ++vv) {
                            pk.us[vv]     = f2bf(acc[2 * kts + 0][fr][vv]);
                            pk.us[4 + vv] = f2bf(acc[2 * kts + 1][fr][vv]);
                        }
                        pend[fr * 2 + kts] = pk.v;
                    }
                }
#pragma unroll
                for (int a2 = 0; a2 < 4; ++a2)
#pragma unroll
                    for (int b2 = 0; b2 < 4; ++b2) {
                        acc[a2][b2][0] = 0.f; acc[a2][b2][1] = 0.f;
                        acc[a2][b2][2] = 0.f; acc[a2][b2][3] = 0.f;
                    }
            }

            // W+B: counted wait (stores stay in flight), raw barrier
            if (!last) {
                if (p > 0) {
                    asm volatile("s_waitcnt vmcnt(2)" ::: "memory");
                } else {
                    asm volatile("s_waitcnt vmcnt(0)" ::: "memory");
                }
                __builtin_amdgcn_sched_barrier(0);
                __builtin_amdgcn_s_barrier();
                __builtin_amdgcn_sched_barrier(0);
            }
        }
    }

    // flush last panel's deferred stores (kernel end drains them)
#pragma unroll
    for (int kt = 0; kt < 4; ++kt) {
        int rg  = r0 + wr + kt * 16 + c16;
        int rgc = rg < cnt ? rg : cnt;
        char* sp = WRb + (size_t)rgc * 131072 + pobase + gq * 16;
        *reinterpret_cast<uint4*>(sp + ubase * 64)       = pend[2 * kt];
        *reinterpret_cast<uint4*>(sp + (ubase + 1) * 64) = pend[2 * kt + 1];
    }
#undef STAGE_W
}

// ---------------- Stage 2: per-bucket MFMA ----------------------------------
__global__ __launch_bounds__(256)
void stage2_kernel(const int* __restrict__ list, const int* __restrict__ offs,
                   const int* __restrict__ ps, const int* __restrict__ qs,
                   const float* __restrict__ P, const float* __restrict__ Q,
                   const unsigned short* __restrict__ WR,
                   float* __restrict__ partial, int r_lo, int B) {
    const int r_rel = blockIdx.x;
    const int r     = r_lo + r_rel;
    const int start = offs[r], end = offs[r + 1];
    if (start >= end) return;
    const int ihalf = blockIdx.y;
    const int t     = threadIdx.x;
    const int lane  = t & 63;
    const int w     = t >> 6;
    const int s     = lane & 15;
    const int kg    = lane >> 4;

    __shared__ float Lq[16][258];
    __shared__ float Lp[16][133];
    __shared__ float red[16][4];

    const unsigned short* Mbase = WR + (size_t)r_rel * NIK;

    for (int s0 = start; s0 < end; s0 += 16) {
        const int ns = min(16, end - s0);
        for (int u = t; u < ns * 64; u += 256) {
            int ss = u >> 6, c = u & 63;
            *reinterpret_cast<float4*>(&Lq[ss][c * 4]) =
                *reinterpret_cast<const float4*>(
                    Q + (size_t)qs[list[s0 + ss]] * DDIM + c * 4);
        }
        for (int u = t; u < ns * 32; u += 256) {
            int ss = u >> 5, c = u & 31;
            *reinterpret_cast<float4*>(&Lp[ss][c * 4]) =
                *reinterpret_cast<const float4*>(
                    P + (size_t)ps[list[s0 + ss]] * DDIM + ihalf * 128 + c * 4);
        }
        __syncthreads();

        bf16x8 bq[8];
#pragma unroll
        for (int kt = 0; kt < 8; ++kt) {
#pragma unroll
            for (int eh = 0; eh < 2; ++eh) {
#pragma unroll
                for (int ev = 0; ev < 4; ++ev) {
                    float v = (s < ns) ? Lq[s][kt * 32 + eh * 16 + kg * 4 + ev]
                                       : 0.f;
                    bq[kt][eh * 4 + ev] = (short)f2bf(v);
                }
            }
        }

        float acc_out = 0.f;
#pragma unroll
        for (int ibl = 0; ibl < 2; ++ibl) {
            const int ibh = w * 2 + ibl;
            const int ibg = ihalf * 8 + ibh;
            // layout: elem = ibg*4096 + row16*256 + kt*32 + kg*8 + e
            const unsigned short* abase =
                Mbase + (size_t)ibg * 4096 + (lane & 15) * 256 + kg * 8;
            bf16x8 af[8];
#pragma unroll
            for (int kt = 0; kt < 8; ++kt)
                af[kt] = *reinterpret_cast<const bf16x8*>(abase + kt * 32);
            f32x4 acc = {0.f, 0.f, 0.f, 0.f};
#pragma unroll
            for (int kt = 0; kt < 8; ++kt)
                acc = __builtin_amdgcn_mfma_f32_16x16x32_bf16(af[kt], bq[kt],
                                                              acc, 0, 0, 0);
#pragma unroll
            for (int reg = 0; reg < 4; ++reg) {
                int il = ibh * 16 + kg * 4 + reg;
                float pv = (s < ns) ? Lp[s][il] : 0.f;
                acc_out += acc[reg] * pv;
            }
        }
        acc_out += __shfl_xor(acc_out, 16, 64);
        acc_out += __shfl_xor(acc_out, 32, 64);
        if (lane < 16) red[s][w] = acc_out;
        __syncthreads();
        if (t < ns)
            partial[(size_t)ihalf * B + list[s0 + t]] =
                red[t][0] + red[t][1] + red[t][2] + red[t][3];
        __syncthreads();
    }
}

// ---------------- final reduce + regularizer --------------------------------
__global__ __launch_bounds__(256)
void sum_out_kernel(const float* __restrict__ partial,
                    const float* __restrict__ norms, float* __restrict__ out,
                    int B) {
    int b = blockIdx.x * 256 + threadIdx.x;
    if (b < B) out[b] = partial[b] + partial[(size_t)B + b];
    if (blockIdx.x == 0 && threadIdx.x == 0)
        out[B] = 0.01f * (sqrtf(norms[0]) + sqrtf(norms[1]) + sqrtf(norms[2]));
}

// ---------------- Launch -----------------------------------------------------
extern "C" void kernel_launch(void* const* d_in, const int* in_sizes, int n_in,
                              void* d_out, int out_size, void* d_ws,
                              size_t ws_size, hipStream_t stream) {
    const int*   ps = (const int*)d_in[0];
    const int*   qs = (const int*)d_in[1];
    const int*   rs = (const int*)d_in[2];
    const float* P  = (const float*)d_in[3];
    const float* Q  = (const float*)d_in[4];
    const float* R  = (const float*)d_in[5];
    const float* W  = (const float*)d_in[6];
    float* out = (float*)d_out;

    const int B      = in_sizes[0];
    const int NUM_RS = in_sizes[5] / DDIM;

    size_t off = 0;
    float* norms = (float*)((char*)d_ws + off);          off += 256;
    int* offs    = (int*)((char*)d_ws + off);            off += (size_t)(NUM_RS + 1) * 4;
    int* list    = (int*)((char*)d_ws + off);            off += (size_t)B * 4;
    off = (off + 255) & ~(size_t)255;
    float* partial = (float*)((char*)d_ws + off);        off += (size_t)NCH2 * B * 4;
    off = (off + 255) & ~(size_t)255;
    unsigned short* Rb = (unsigned short*)((char*)d_ws + off);
    off += (size_t)NUM_RS * DDIM * 2;
    off = (off + 255) & ~(size_t)255;
    unsigned short* Wt = (unsigned short*)((char*)d_ws + off);
    off += (size_t)NIK * DDIM * 2;
    off = (off + 255) & ~(size_t)255;
    unsigned short* WR = (unsigned short*)((char*)d_ws + off);

    size_t wr_bytes = (ws_size > off) ? ws_size - off : 0;
    int max_chunk = (int)(wr_bytes / ((size_t)NIK * 2)) - 1;  // +1 dump row
    if (max_chunk > NUM_RS) max_chunk = NUM_RS;
    if (max_chunk < 1) max_chunk = 1;

    fused_csr_kernel<<<1, 1024, 0, stream>>>(rs, offs, list, norms, B, NUM_RS);
    norm_kernel<<<dim3(128, 4), 256, 0, stream>>>(ps, qs, rs, P, Q, R, Rb,
                                                  norms, B, NUM_RS * DDIM / 4);
    conv_wt_kernel<<<dim3(4, 2, DDIM), 256, 0, stream>>>(W, Wt);

    for (int lo = 0; lo < NUM_RS; lo += max_chunk) {
        int cnt = NUM_RS - lo;
        if (cnt > max_chunk) cnt = max_chunk;
        // (64 strips, r-blocks): id = strip + rblk*64 -> XCD = strip%8
        dim3 g1(NIK / BN / NPANEL, (cnt + BM - 1) / BM);
        stage1_kernel<<<g1, 256, 0, stream>>>(Rb, Wt, WR, lo, cnt);
        stage2_kernel<<<dim3(cnt, NCH2), 256, 0, stream>>>(
            list, offs, ps, qs, P, Q, WR, partial, lo, B);
    }
    sum_out_kernel<<<(B + 255) / 256, 256, 0, stream>>>(partial, norms, out, B);
}

// Round 23
// 146.909 us; speedup vs baseline: 1.1629x; 1.1629x over previous
//
#include <hip/hip_runtime.h>
#include <hip/hip_bf16.h>

// TuckER: out[b] = sum_{i,j,k} p[b,i] r[b,j] q[b,k] W[i,j,k]
// Pipeline (6 launches):
//   fused_csr: counts->scan->fill in ONE block (LDS); zeroes norm accum
//   norm:      REG norms (which 0..2) + conv_r fp32->bf16 (which==3)
//   conv_wt:   W[i][j][k] fp32 -> Wt[(i,k)][j] bf16 (transpose)
//   stage1:    WR[r,(i,k)] = sum_j R[r,j] Wt[(ik),j]  MFMA bf16 GEMM.
//              PERSISTENT-STRIP, BM=64: grid (64 strips, 16 r-blocks) =
//              1024 blocks = 4 blocks/CU (16 waves/CU -- 2x TLP vs BM=128;
//              barrier stalls of one block overlap compute of 3 others).
//              XCD co-location: id = strip + rblk*64, XCD = strip%8; per-XCD
//              Wt set = 8 strips x 8 panels x 64KB = 4MB = L2, now shared by
//              16 r-blocks. REGISTER-RESIDENT R (16 bf16x8/thread).
//              Plain 2-buffer staging + __syncthreads (R16/21/22: all
//              fancier schedules null or regress).
//              WR layout (bytes): r*131072 + (i>>4)*8192 + (i&15)*512
//                                 + (k>>5)*64 + [granule: g*16 + e*2]
//              where k&31 = (e>>2)*16 + g*4 + (e&3)
//   stage2:    per-bucket MFMA: A = WR frags (streamed), B = q (16 samples)
//   sum_out:   out[b] = partial halves; also writes out[B] (reg term)

#define DDIM 256
#define NIK  65536
#define BM   64
#define BN   128
#define BK   64
#define NCH2 2
#define NPANEL 8

typedef unsigned int uint;
typedef __attribute__((ext_vector_type(8))) short bf16x8;
typedef __attribute__((ext_vector_type(4))) float f32x4;

static __device__ __forceinline__ unsigned short f2bf(float f) {
    __hip_bfloat16 h = __float2bfloat16(f);
    return *reinterpret_cast<unsigned short*>(&h);
}
static __device__ __forceinline__ float bf2f(unsigned short u) {
    return __uint_as_float(((uint)u) << 16);
}

#define GLOAD_LDS16(gsrc, ldst)                                                \
    __builtin_amdgcn_global_load_lds(                                          \
        (const __attribute__((address_space(1))) void*)(gsrc),                 \
        (__attribute__((address_space(3))) void*)(ldst), 16, 0, 0)

// ---------------- fused CSR: prep+hist+scan+fill in one block ---------------
__global__ __launch_bounds__(1024)
void fused_csr_kernel(const int* __restrict__ rs, int* __restrict__ offs,
                      int* __restrict__ list, float* __restrict__ norms,
                      int B, int n) {
    __shared__ int cnt[1024];
    __shared__ int buf[2][1024];
    const int t = threadIdx.x;
    if (t < 3) norms[t] = 0.f;
    cnt[t] = 0;
    __syncthreads();
    for (int b = t; b < B; b += 1024) atomicAdd(&cnt[rs[b]], 1);
    __syncthreads();
    const int myc = cnt[t];
    int cur = 0;
    buf[0][t] = (t < n) ? myc : 0;
    __syncthreads();
    for (int d = 1; d < 1024; d <<= 1) {
        int x = buf[cur][t] + ((t >= d) ? buf[cur][t - d] : 0);
        buf[cur ^ 1][t] = x;
        cur ^= 1;
        __syncthreads();
    }
    if (t < n) {
        int inc = buf[cur][t];
        offs[t + 1] = inc;
        if (t == 0) offs[0] = 0;
        cnt[t] = inc - myc;  // exclusive start -> fill cursor
    }
    __syncthreads();
    for (int b = t; b < B; b += 1024) {
        int pos = atomicAdd(&cnt[rs[b]], 1);
        list[pos] = b;
    }
}

// ---------------- Norms (which 0..2) + conv_r (which==3) --------------------
__global__ __launch_bounds__(256)
void norm_kernel(const int* __restrict__ ps, const int* __restrict__ qs,
                 const int* __restrict__ rs, const float* __restrict__ P,
                 const float* __restrict__ Q, const float* __restrict__ R,
                 unsigned short* __restrict__ Rb, float* __restrict__ accum,
                 int B, int n4) {
    const int which = blockIdx.y;
    if (which == 3) {
        for (int idx = blockIdx.x * 256 + threadIdx.x; idx < n4;
             idx += 128 * 256) {
            float4 v = *reinterpret_cast<const float4*>(R + idx * 4);
            ushort4 o;
            o.x = f2bf(v.x); o.y = f2bf(v.y); o.z = f2bf(v.z); o.w = f2bf(v.w);
            *reinterpret_cast<ushort4*>(Rb + idx * 4) = o;
        }
        return;
    }
    const int*   idx = (which == 0) ? ps : (which == 1) ? qs : rs;
    const float* tab = (which == 0) ? P : (which == 1) ? Q : R;
    float a = 0.f;
    const int total = B * 64;
    for (int e = blockIdx.x * 256 + threadIdx.x; e < total; e += 128 * 256) {
        int b = e >> 6, cc = e & 63;
        float4 v = *reinterpret_cast<const float4*>(tab + (size_t)idx[b] * DDIM + cc * 4);
        a += v.x * v.x + v.y * v.y + v.z * v.z + v.w * v.w;
    }
#pragma unroll
    for (int off = 32; off; off >>= 1) a += __shfl_down(a, off, 64);
    __shared__ float red[4];
    if ((threadIdx.x & 63) == 0) red[threadIdx.x >> 6] = a;
    __syncthreads();
    if (threadIdx.x == 0) atomicAdd(accum + which, red[0] + red[1] + red[2] + red[3]);
}

// ---------------- transpose-convert W: [i][j][k] f32 -> [(i,k)][j] bf16 -----
__global__ __launch_bounds__(256)
void conv_wt_kernel(const float* __restrict__ W, unsigned short* __restrict__ Wt) {
    const int k0 = blockIdx.x * 64;
    const int j0 = blockIdx.y * 128;
    const int i  = blockIdx.z;
    const int t  = threadIdx.x;

    __shared__ float sT[64][129];

    const float* Wi = W + (size_t)i * NIK;
#pragma unroll
    for (int it = 0; it < 8; ++it) {
        int slot = it * 256 + t;
        int jj = slot >> 4, c = slot & 15;
        float4 v = *reinterpret_cast<const float4*>(
            Wi + (size_t)(j0 + jj) * DDIM + k0 + c * 4);
        sT[c * 4 + 0][jj] = v.x;
        sT[c * 4 + 1][jj] = v.y;
        sT[c * 4 + 2][jj] = v.z;
        sT[c * 4 + 3][jj] = v.w;
    }
    __syncthreads();
#pragma unroll
    for (int it = 0; it < 4; ++it) {
        int u = it * 256 + t;
        int kk = u >> 4, jg = u & 15;
        union { unsigned short us[8]; uint4 v; } pk;
#pragma unroll
        for (int m = 0; m < 8; ++m) pk.us[m] = f2bf(sT[kk][jg * 8 + m]);
        *reinterpret_cast<uint4*>(
            Wt + (size_t)(i * DDIM + k0 + kk) * DDIM + j0 + jg * 8) = pk.v;
    }
}

// ---------------- Stage 1: persistent-strip BM=64, R in regs, 4 blocks/CU ---
__global__ __launch_bounds__(256, 4)
void stage1_kernel(const unsigned short* __restrict__ Rb,
                   const unsigned short* __restrict__ Wt,
                   unsigned short* __restrict__ WR,
                   int r_lo, int cnt) {
    const int t     = threadIdx.x;
    const int lane  = t & 63;
    const int wid   = t >> 6;
    const int strip = blockIdx.x;        // 0..63 ; XCD = strip%8
    const int r0    = blockIdx.y * BM;

    __shared__ char smem[32768];   // [B0|B1] 16KB each (Wt staging only)

    const int wr = (wid >> 1) * 32;  // wave r offset (0 or 32)
    const int wn = (wid & 1) * 64;   // wave ik offset (0 or 64)

    // ---- load R fragments once: 8 K-slices x 2 row-frags = 16 bf16x8 ------
    bf16x8 rfrag[8][2];
    {
#pragma unroll
        for (int rd = 0; rd < 4; ++rd) {   // K=64 slice rd: 64r x 64j = 8KB
            const int j0s = rd * BK;
            __syncthreads();  // buffer free (prev slice's reads done)
#pragma unroll
            for (int c = 0; c < 2; ++c) {
                int u = c * 256 + t;
                int row = u >> 3, g = u & 7;
                int rg = r0 + row;
                if (rg >= cnt) rg = 0;
                GLOAD_LDS16(Rb + (size_t)(r_lo + rg) * DDIM + j0s +
                                ((g ^ (row & 7)) << 3),
                            smem + u * 16);
            }
            __syncthreads();  // staged
#pragma unroll
            for (int ks = 0; ks < 2; ++ks) {
                const int jg = ks * 4 + (lane >> 4);
#pragma unroll
                for (int f = 0; f < 2; ++f) {
                    int rowA = wr + f * 16 + (lane & 15);
                    rfrag[rd * 2 + ks][f] = *reinterpret_cast<const bf16x8*>(
                        smem + rowA * 128 + ((jg ^ (rowA & 7)) << 4));
                }
            }
        }
        __syncthreads();  // all rfrag reads done before B staging reuses smem
    }

    f32x4 acc[4][2];
#pragma unroll
    for (int a = 0; a < 4; ++a)
#pragma unroll
        for (int b = 0; b < 2; ++b) {
            acc[a][b][0] = 0.f; acc[a][b][1] = 0.f;
            acc[a][b][2] = 0.f; acc[a][b][3] = 0.f;
        }

    // stage Wt for (panel p, kt) into buffer offset boff (0 or 16384)
#define STAGE_W(p, kt, boff)                                                    \
    {                                                                           \
        const int j0s = (kt) * BK;                                              \
        const int n0s = strip * (BN * NPANEL) + (p) * BN;                       \
        _Pragma("unroll")                                                       \
        for (int c = 0; c < 4; ++c) {                                           \
            int u = c * 256 + t;                                                \
            int row = u >> 3, g = u & 7;                                        \
            GLOAD_LDS16(Wt + (size_t)(n0s + row) * DDIM + j0s +                 \
                            ((g ^ (row & 7)) << 3),                             \
                        smem + (boff) + u * 16);                                \
        }                                                                       \
    }

    STAGE_W(0, 0, 0);
    __syncthreads();  // drain prologue

    const int c16   = lane & 15;
    const int gq    = lane >> 4;
    const int ubase = wn >> 5;  // 0 or 2
    char* WRb = (char*)WR;

    for (int p = 0; p < NPANEL; ++p) {
#pragma unroll
        for (int kt = 0; kt < 4; ++kt) {
            const int coff = (kt & 1) << 14;   // static per unrolled kt
            // issue next step's Wt staging (kt+1, or next panel's kt=0)
            if (kt < 3) {
                STAGE_W(p, kt + 1, coff ^ 16384);
            } else if (p < NPANEL - 1) {
                STAGE_W(p + 1, 0, coff ^ 16384);
            }

            char* Bcur = smem + coff;
#pragma unroll
            for (int ks = 0; ks < 2; ++ks) {
                bf16x8 a[4];
                const int jg = ks * 4 + (lane >> 4);
#pragma unroll
                for (int f = 0; f < 4; ++f) {
                    int rowB = wn + f * 16 + (lane & 15);
                    a[f] = *reinterpret_cast<const bf16x8*>(
                        Bcur + rowB * 128 + ((jg ^ (rowB & 7)) << 4));
                }
#pragma unroll
                for (int fi = 0; fi < 4; ++fi)
#pragma unroll
                    for (int fr = 0; fr < 2; ++fr)
                        acc[fi][fr] = __builtin_amdgcn_mfma_f32_16x16x32_bf16(
                            a[fi], rfrag[kt * 2 + ks][fr], acc[fi][fr],
                            0, 0, 0);
            }

            if (kt == 3) {
                // epilogue for panel p : direct 16B stores from regs.
                const int n0  = strip * (BN * NPANEL) + p * BN;
                const int i_g = n0 >> 8;
                const size_t obase = (size_t)(i_g >> 4) * 8192 +
                                     (size_t)(i_g & 15) * 512 +
                                     (size_t)(n0 & 255) * 2;
#pragma unroll
                for (int fr = 0; fr < 2; ++fr) {
                    int rg = r0 + wr + fr * 16 + c16;
                    if (rg < cnt) {
#pragma unroll
                        for (int kts = 0; kts < 2; ++kts) {
                            union { unsigned short us[8]; uint4 v; } pk;
#pragma unroll
                            for (int vv = 0; vv < 4; ++vv) {
                                pk.us[vv]     = f2bf(acc[2 * kts + 0][fr][vv]);
                                pk.us[4 + vv] = f2bf(acc[2 * kts + 1][fr][vv]);
                            }
                            *reinterpret_cast<uint4*>(
                                WRb + (size_t)rg * 131072 + obase +
                                (ubase + kts) * 64 + gq * 16) = pk.v;
                        }
                    }
                }
#pragma unroll
                for (int a2 = 0; a2 < 4; ++a2)
#pragma unroll
                    for (int b2 = 0; b2 < 2; ++b2) {
                        acc[a2][b2][0] = 0.f; acc[a2][b2][1] = 0.f;
                        acc[a2][b2][2] = 0.f; acc[a2][b2][3] = 0.f;
                    }
            }
            __syncthreads();  // next-step staging (and stores) drained
        }
    }
#undef STAGE_W
}

// ---------------- Stage 2: per-bucket MFMA ----------------------------------
__global__ __launch_bounds__(256)
void stage2_kernel(const int* __restrict__ list, const int* __restrict__ offs,
                   const int* __restrict__ ps, const int* __restrict__ qs,
                   const float* __restrict__ P, const float* __restrict__ Q,
                   const unsigned short* __restrict__ WR,
                   float* __restrict__ partial, int r_lo, int B) {
    const int r_rel = blockIdx.x;
    const int r     = r_lo + r_rel;
    const int start = offs[r], end = offs[r + 1];
    if (start >= end) return;
    const int ihalf = blockIdx.y;
    const int t     = threadIdx.x;
    const int lane  = t & 63;
    const int w     = t >> 6;
    const int s     = lane & 15;
    const int kg    = lane >> 4;

    __shared__ float Lq[16][258];
    __shared__ float Lp[16][133];
    __shared__ float red[16][4];

    const unsigned short* Mbase = WR + (size_t)r_rel * NIK;

    for (int s0 = start; s0 < end; s0 += 16) {
        const int ns = min(16, end - s0);
        for (int u = t; u < ns * 64; u += 256) {
            int ss = u >> 6, c = u & 63;
            *reinterpret_cast<float4*>(&Lq[ss][c * 4]) =
                *reinterpret_cast<const float4*>(
                    Q + (size_t)qs[list[s0 + ss]] * DDIM + c * 4);
        }
        for (int u = t; u < ns * 32; u += 256) {
            int ss = u >> 5, c = u & 31;
            *reinterpret_cast<float4*>(&Lp[ss][c * 4]) =
                *reinterpret_cast<const float4*>(
                    P + (size_t)ps[list[s0 + ss]] * DDIM + ihalf * 128 + c * 4);
        }
        __syncthreads();

        bf16x8 bq[8];
#pragma unroll
        for (int kt = 0; kt < 8; ++kt) {
#pragma unroll
            for (int eh = 0; eh < 2; ++eh) {
#pragma unroll
                for (int ev = 0; ev < 4; ++ev) {
                    float v = (s < ns) ? Lq[s][kt * 32 + eh * 16 + kg * 4 + ev]
                                       : 0.f;
                    bq[kt][eh * 4 + ev] = (short)f2bf(v);
                }
            }
        }

        float acc_out = 0.f;
#pragma unroll
        for (int ibl = 0; ibl < 2; ++ibl) {
            const int ibh = w * 2 + ibl;
            const int ibg = ihalf * 8 + ibh;
            // layout: elem = ibg*4096 + row16*256 + kt*32 + kg*8 + e
            const unsigned short* abase =
                Mbase + (size_t)ibg * 4096 + (lane & 15) * 256 + kg * 8;
            bf16x8 af[8];
#pragma unroll
            for (int kt = 0; kt < 8; ++kt)
                af[kt] = *reinterpret_cast<const bf16x8*>(abase + kt * 32);
            f32x4 acc = {0.f, 0.f, 0.f, 0.f};
#pragma unroll
            for (int kt = 0; kt < 8; ++kt)
                acc = __builtin_amdgcn_mfma_f32_16x16x32_bf16(af[kt], bq[kt],
                                                              acc, 0, 0, 0);
#pragma unroll
            for (int reg = 0; reg < 4; ++reg) {
                int il = ibh * 16 + kg * 4 + reg;
                float pv = (s < ns) ? Lp[s][il] : 0.f;
                acc_out += acc[reg] * pv;
            }
        }
        acc_out += __shfl_xor(acc_out, 16, 64);
        acc_out += __shfl_xor(acc_out, 32, 64);
        if (lane < 16) red[s][w] = acc_out;
        __syncthreads();
        if (t < ns)
            partial[(size_t)ihalf * B + list[s0 + t]] =
                red[t][0] + red[t][1] + red[t][2] + red[t][3];
        __syncthreads();
    }
}

// ---------------- final reduce + regularizer --------------------------------
__global__ __launch_bounds__(256)
void sum_out_kernel(const float* __restrict__ partial,
                    const float* __restrict__ norms, float* __restrict__ out,
                    int B) {
    int b = blockIdx.x * 256 + threadIdx.x;
    if (b < B) out[b] = partial[b] + partial[(size_t)B + b];
    if (blockIdx.x == 0 && threadIdx.x == 0)
        out[B] = 0.01f * (sqrtf(norms[0]) + sqrtf(norms[1]) + sqrtf(norms[2]));
}

// ---------------- Launch -----------------------------------------------------
extern "C" void kernel_launch(void* const* d_in, const int* in_sizes, int n_in,
                              void* d_out, int out_size, void* d_ws,
                              size_t ws_size, hipStream_t stream) {
    const int*   ps = (const int*)d_in[0];
    const int*   qs = (const int*)d_in[1];
    const int*   rs = (const int*)d_in[2];
    const float* P  = (const float*)d_in[3];
    const float* Q  = (const float*)d_in[4];
    const float* R  = (const float*)d_in[5];
    const float* W  = (const float*)d_in[6];
    float* out = (float*)d_out;

    const int B      = in_sizes[0];
    const int NUM_RS = in_sizes[5] / DDIM;

    size_t off = 0;
    float* norms = (float*)((char*)d_ws + off);          off += 256;
    int* offs    = (int*)((char*)d_ws + off);            off += (size_t)(NUM_RS + 1) * 4;
    int* list    = (int*)((char*)d_ws + off);            off += (size_t)B * 4;
    off = (off + 255) & ~(size_t)255;
    float* partial = (float*)((char*)d_ws + off);        off += (size_t)NCH2 * B * 4;
    off = (off + 255) & ~(size_t)255;
    unsigned short* Rb = (unsigned short*)((char*)d_ws + off);
    off += (size_t)NUM_RS * DDIM * 2;
    off = (off + 255) & ~(size_t)255;
    unsigned short* Wt = (unsigned short*)((char*)d_ws + off);
    off += (size_t)NIK * DDIM * 2;
    off = (off + 255) & ~(size_t)255;
    unsigned short* WR = (unsigned short*)((char*)d_ws + off);

    size_t wr_bytes = (ws_size > off) ? ws_size - off : 0;
    int max_chunk = (int)(wr_bytes / ((size_t)NIK * 2));
    if (max_chunk > NUM_RS) max_chunk = NUM_RS;
    if (max_chunk < 1) max_chunk = 1;

    fused_csr_kernel<<<1, 1024, 0, stream>>>(rs, offs, list, norms, B, NUM_RS);
    norm_kernel<<<dim3(128, 4), 256, 0, stream>>>(ps, qs, rs, P, Q, R, Rb,
                                                  norms, B, NUM_RS * DDIM / 4);
    conv_wt_kernel<<<dim3(4, 2, DDIM), 256, 0, stream>>>(W, Wt);

    for (int lo = 0; lo < NUM_RS; lo += max_chunk) {
        int cnt = NUM_RS - lo;
        if (cnt > max_chunk) cnt = max_chunk;
        // (64 strips, 16 r-blocks): id = strip + rblk*64 -> XCD = strip%8
        dim3 g1(NIK / BN / NPANEL, (cnt + BM - 1) / BM);
        stage1_kernel<<<g1, 256, 0, stream>>>(Rb, Wt, WR, lo, cnt);
        stage2_kernel<<<dim3(cnt, NCH2), 256, 0, stream>>>(
            list, offs, ps, qs, P, Q, WR, partial, lo, B);
    }
    sum_out_kernel<<<(B + 255) / 256, 256, 0, stream>>>(partial, norms, out, B);
}

// Round 24
// 118.307 us; speedup vs baseline: 1.4440x; 1.2418x over previous
//
#include <hip/hip_runtime.h>
#include <hip/hip_bf16.h>

// TuckER: out[b] = sum_{i,j,k} p[b,i] r[b,j] q[b,k] W[i,j,k]
// Pipeline (6 launches):
//   fused_csr: counts->scan->fill in ONE block (LDS); zeroes norm accum
//   norm:      REG norms (which 0..2) + conv_r fp32->bf16 (which==3)
//   conv_wt:   W[i][j][k] fp32 -> Wt[(i,k)][j] bf16 (transpose)
//   stage1:    WR[r,(i,k)] = sum_j R[r,j] Wt[(ik),j]  MFMA bf16 GEMM.
//              PERSISTENT-STRIP (64 strips x 8 r-blocks, lockstep panels,
//              XCD co-location: Wt/XCD = 4MB = L2). REGISTER-RESIDENT R
//              (32 bf16x8/thread loaded once). DOUBLE-STEP staging: 4x16KB
//              LDS buffers, each step stages TWO kt-tiles and computes two,
//              ONE barrier per double-step (33 -> 17 barrier drains).
//              Regular (cached) stores: R20 showed NT stores push WR out of
//              L2/L3 and stage2 regresses 25 -> 66 us. This config is the
//              empirical optimum: counted-vmcnt (R16), panel rotation (R14),
//              epilogue fusion (R13), direct-L2 frags (R18), NT (R20),
//              deferred-spread stores (R22), BM=64 (R23) all null/regress.
//              WR layout (bytes): r*131072 + (i>>4)*8192 + (i&15)*512
//                                 + (k>>5)*64 + [granule: g*16 + e*2]
//              where k&31 = (e>>2)*16 + g*4 + (e&3)
//   stage2:    per-bucket MFMA: A = WR frags (streamed), B = q (16 samples)
//   sum_out:   out[b] = partial halves; also writes out[B] (reg term)

#define DDIM 256
#define NIK  65536
#define BM   128
#define BN   128
#define BK   64
#define NCH2 2
#define NPANEL 8

typedef unsigned int uint;
typedef __attribute__((ext_vector_type(8))) short bf16x8;
typedef __attribute__((ext_vector_type(4))) float f32x4;

static __device__ __forceinline__ unsigned short f2bf(float f) {
    __hip_bfloat16 h = __float2bfloat16(f);
    return *reinterpret_cast<unsigned short*>(&h);
}
static __device__ __forceinline__ float bf2f(unsigned short u) {
    return __uint_as_float(((uint)u) << 16);
}

#define GLOAD_LDS16(gsrc, ldst)                                                \
    __builtin_amdgcn_global_load_lds(                                          \
        (const __attribute__((address_space(1))) void*)(gsrc),                 \
        (__attribute__((address_space(3))) void*)(ldst), 16, 0, 0)

// ---------------- fused CSR: prep+hist+scan+fill in one block ---------------
__global__ __launch_bounds__(1024)
void fused_csr_kernel(const int* __restrict__ rs, int* __restrict__ offs,
                      int* __restrict__ list, float* __restrict__ norms,
                      int B, int n) {
    __shared__ int cnt[1024];
    __shared__ int buf[2][1024];
    const int t = threadIdx.x;
    if (t < 3) norms[t] = 0.f;
    cnt[t] = 0;
    __syncthreads();
    for (int b = t; b < B; b += 1024) atomicAdd(&cnt[rs[b]], 1);
    __syncthreads();
    const int myc = cnt[t];
    int cur = 0;
    buf[0][t] = (t < n) ? myc : 0;
    __syncthreads();
    for (int d = 1; d < 1024; d <<= 1) {
        int x = buf[cur][t] + ((t >= d) ? buf[cur][t - d] : 0);
        buf[cur ^ 1][t] = x;
        cur ^= 1;
        __syncthreads();
    }
    if (t < n) {
        int inc = buf[cur][t];
        offs[t + 1] = inc;
        if (t == 0) offs[0] = 0;
        cnt[t] = inc - myc;  // exclusive start -> fill cursor
    }
    __syncthreads();
    for (int b = t; b < B; b += 1024) {
        int pos = atomicAdd(&cnt[rs[b]], 1);
        list[pos] = b;
    }
}

// ---------------- Norms (which 0..2) + conv_r (which==3) --------------------
__global__ __launch_bounds__(256)
void norm_kernel(const int* __restrict__ ps, const int* __restrict__ qs,
                 const int* __restrict__ rs, const float* __restrict__ P,
                 const float* __restrict__ Q, const float* __restrict__ R,
                 unsigned short* __restrict__ Rb, float* __restrict__ accum,
                 int B, int n4) {
    const int which = blockIdx.y;
    if (which == 3) {
        for (int idx = blockIdx.x * 256 + threadIdx.x; idx < n4;
             idx += 128 * 256) {
            float4 v = *reinterpret_cast<const float4*>(R + idx * 4);
            ushort4 o;
            o.x = f2bf(v.x); o.y = f2bf(v.y); o.z = f2bf(v.z); o.w = f2bf(v.w);
            *reinterpret_cast<ushort4*>(Rb + idx * 4) = o;
        }
        return;
    }
    const int*   idx = (which == 0) ? ps : (which == 1) ? qs : rs;
    const float* tab = (which == 0) ? P : (which == 1) ? Q : R;
    float a = 0.f;
    const int total = B * 64;
    for (int e = blockIdx.x * 256 + threadIdx.x; e < total; e += 128 * 256) {
        int b = e >> 6, cc = e & 63;
        float4 v = *reinterpret_cast<const float4*>(tab + (size_t)idx[b] * DDIM + cc * 4);
        a += v.x * v.x + v.y * v.y + v.z * v.z + v.w * v.w;
    }
#pragma unroll
    for (int off = 32; off; off >>= 1) a += __shfl_down(a, off, 64);
    __shared__ float red[4];
    if ((threadIdx.x & 63) == 0) red[threadIdx.x >> 6] = a;
    __syncthreads();
    if (threadIdx.x == 0) atomicAdd(accum + which, red[0] + red[1] + red[2] + red[3]);
}

// ---------------- transpose-convert W: [i][j][k] f32 -> [(i,k)][j] bf16 -----
__global__ __launch_bounds__(256)
void conv_wt_kernel(const float* __restrict__ W, unsigned short* __restrict__ Wt) {
    const int k0 = blockIdx.x * 64;
    const int j0 = blockIdx.y * 128;
    const int i  = blockIdx.z;
    const int t  = threadIdx.x;

    __shared__ float sT[64][129];

    const float* Wi = W + (size_t)i * NIK;
#pragma unroll
    for (int it = 0; it < 8; ++it) {
        int slot = it * 256 + t;
        int jj = slot >> 4, c = slot & 15;
        float4 v = *reinterpret_cast<const float4*>(
            Wi + (size_t)(j0 + jj) * DDIM + k0 + c * 4);
        sT[c * 4 + 0][jj] = v.x;
        sT[c * 4 + 1][jj] = v.y;
        sT[c * 4 + 2][jj] = v.z;
        sT[c * 4 + 3][jj] = v.w;
    }
    __syncthreads();
#pragma unroll
    for (int it = 0; it < 4; ++it) {
        int u = it * 256 + t;
        int kk = u >> 4, jg = u & 15;
        union { unsigned short us[8]; uint4 v; } pk;
#pragma unroll
        for (int m = 0; m < 8; ++m) pk.us[m] = f2bf(sT[kk][jg * 8 + m]);
        *reinterpret_cast<uint4*>(
            Wt + (size_t)(i * DDIM + k0 + kk) * DDIM + j0 + jg * 8) = pk.v;
    }
}

// ---------------- Stage 1: persistent-strip, R in regs, double-step ---------
__global__ __launch_bounds__(256, 2)
void stage1_kernel(const unsigned short* __restrict__ Rb,
                   const unsigned short* __restrict__ Wt,
                   unsigned short* __restrict__ WR,
                   int r_lo, int cnt) {
    const int t     = threadIdx.x;
    const int lane  = t & 63;
    const int wid   = t >> 6;
    const int strip = blockIdx.x;        // 0..63 ; XCD = strip%8
    const int r0    = blockIdx.y * BM;

    __shared__ char smem[65536];   // 4 x 16KB Wt buffers (pairs per dstep)

    const int wr = (wid >> 1) * 64;
    const int wn = (wid & 1) * 64;

    // ---- load R fragments once: 8 K-slices x 4 row-frags = 32 bf16x8 ------
    bf16x8 rfrag[8][4];
    {
#pragma unroll
        for (int rd = 0; rd < 4; ++rd) {   // K=64 slice rd
            const int j0s = rd * BK;
            __syncthreads();  // buffer free (prev slice's reads done)
#pragma unroll
            for (int c = 0; c < 4; ++c) {
                int u = c * 256 + t;
                int row = u >> 3, g = u & 7;
                int rg = r0 + row;
                if (rg >= cnt) rg = 0;
                GLOAD_LDS16(Rb + (size_t)(r_lo + rg) * DDIM + j0s +
                                ((g ^ (row & 7)) << 3),
                            smem + u * 16);
            }
            __syncthreads();  // staged
#pragma unroll
            for (int ks = 0; ks < 2; ++ks) {
                const int jg = ks * 4 + (lane >> 4);
#pragma unroll
                for (int f = 0; f < 4; ++f) {
                    int rowA = wr + f * 16 + (lane & 15);
                    rfrag[rd * 2 + ks][f] = *reinterpret_cast<const bf16x8*>(
                        smem + rowA * 128 + ((jg ^ (rowA & 7)) << 4));
                }
            }
        }
        __syncthreads();  // all rfrag reads done before B staging reuses smem
    }

    f32x4 acc[4][4];
#pragma unroll
    for (int a = 0; a < 4; ++a)
#pragma unroll
        for (int b = 0; b < 4; ++b) {
            acc[a][b][0] = 0.f; acc[a][b][1] = 0.f;
            acc[a][b][2] = 0.f; acc[a][b][3] = 0.f;
        }

    // stage GLOBAL kt index ktg (0..31) into LDS byte offset boff
#define STAGE_W1(ktg, boff)                                                     \
    {                                                                           \
        const int j0s = ((ktg) & 3) * BK;                                       \
        const int n0s = strip * (BN * NPANEL) + ((ktg) >> 2) * BN;              \
        _Pragma("unroll")                                                       \
        for (int c = 0; c < 4; ++c) {                                           \
            int u = c * 256 + t;                                                \
            int row = u >> 3, g = u & 7;                                        \
            GLOAD_LDS16(Wt + (size_t)(n0s + row) * DDIM + j0s +                 \
                            ((g ^ (row & 7)) << 3),                             \
                        smem + (boff) + u * 16);                                \
        }                                                                       \
    }

    STAGE_W1(0, 0);
    STAGE_W1(1, 16384);
    __syncthreads();  // drain prologue

    const int c16   = lane & 15;
    const int gq    = lane >> 4;
    const int ubase = wn >> 5;  // 0 or 2
    char* WRb = (char*)WR;

    for (int p = 0; p < NPANEL; ++p) {
#pragma unroll
        for (int dh = 0; dh < 2; ++dh) {     // double-step within panel
            const int d    = p * 2 + dh;     // global double-step 0..15
            const int coff = dh << 15;       // pair base: 0 or 32768 (static)
            const int noff = coff ^ 32768;
            if (d < 15) {
                STAGE_W1(2 * d + 2, noff);
                STAGE_W1(2 * d + 3, noff + 16384);
            }

#pragma unroll
            for (int j = 0; j < 2; ++j) {    // the two kt-tiles of this dstep
                const int kt = dh * 2 + j;   // static
                char* Bcur = smem + coff + (j << 14);
#pragma unroll
                for (int ks = 0; ks < 2; ++ks) {
                    bf16x8 a[4];
                    const int jg = ks * 4 + (lane >> 4);
#pragma unroll
                    for (int f = 0; f < 4; ++f) {
                        int rowB = wn + f * 16 + (lane & 15);
                        a[f] = *reinterpret_cast<const bf16x8*>(
                            Bcur + rowB * 128 + ((jg ^ (rowB & 7)) << 4));
                    }
#pragma unroll
                    for (int fi = 0; fi < 4; ++fi)
#pragma unroll
                        for (int fr = 0; fr < 4; ++fr)
                            acc[fi][fr] =
                                __builtin_amdgcn_mfma_f32_16x16x32_bf16(
                                    a[fi], rfrag[kt * 2 + ks][fr],
                                    acc[fi][fr], 0, 0, 0);
                }
            }

            if (dh == 1) {
                // epilogue for panel p : direct 16B stores from regs.
                const int n0  = strip * (BN * NPANEL) + p * BN;
                const int i_g = n0 >> 8;
                const size_t obase = (size_t)(i_g >> 4) * 8192 +
                                     (size_t)(i_g & 15) * 512 +
                                     (size_t)(n0 & 255) * 2;
#pragma unroll
                for (int fr = 0; fr < 4; ++fr) {
                    int rg = r0 + wr + fr * 16 + c16;
                    if (rg < cnt) {
#pragma unroll
                        for (int kts = 0; kts < 2; ++kts) {
                            union { unsigned short us[8]; uint4 v; } pk;
#pragma unroll
                            for (int vv = 0; vv < 4; ++vv) {
                                pk.us[vv]     = f2bf(acc[2 * kts + 0][fr][vv]);
                                pk.us[4 + vv] = f2bf(acc[2 * kts + 1][fr][vv]);
                            }
                            *reinterpret_cast<uint4*>(
                                WRb + (size_t)rg * 131072 + obase +
                                (ubase + kts) * 64 + gq * 16) = pk.v;
                        }
                    }
                }
#pragma unroll
                for (int a2 = 0; a2 < 4; ++a2)
#pragma unroll
                    for (int b2 = 0; b2 < 4; ++b2) {
                        acc[a2][b2][0] = 0.f; acc[a2][b2][1] = 0.f;
                        acc[a2][b2][2] = 0.f; acc[a2][b2][3] = 0.f;
                    }
            }
            __syncthreads();  // next-dstep staging (and stores) drained
        }
    }
#undef STAGE_W1
}

// ---------------- Stage 2: per-bucket MFMA ----------------------------------
__global__ __launch_bounds__(256)
void stage2_kernel(const int* __restrict__ list, const int* __restrict__ offs,
                   const int* __restrict__ ps, const int* __restrict__ qs,
                   const float* __restrict__ P, const float* __restrict__ Q,
                   const unsigned short* __restrict__ WR,
                   float* __restrict__ partial, int r_lo, int B) {
    const int r_rel = blockIdx.x;
    const int r     = r_lo + r_rel;
    const int start = offs[r], end = offs[r + 1];
    if (start >= end) return;
    const int ihalf = blockIdx.y;
    const int t     = threadIdx.x;
    const int lane  = t & 63;
    const int w     = t >> 6;
    const int s     = lane & 15;
    const int kg    = lane >> 4;

    __shared__ float Lq[16][258];
    __shared__ float Lp[16][133];
    __shared__ float red[16][4];

    const unsigned short* Mbase = WR + (size_t)r_rel * NIK;

    for (int s0 = start; s0 < end; s0 += 16) {
        const int ns = min(16, end - s0);
        for (int u = t; u < ns * 64; u += 256) {
            int ss = u >> 6, c = u & 63;
            *reinterpret_cast<float4*>(&Lq[ss][c * 4]) =
                *reinterpret_cast<const float4*>(
                    Q + (size_t)qs[list[s0 + ss]] * DDIM + c * 4);
        }
        for (int u = t; u < ns * 32; u += 256) {
            int ss = u >> 5, c = u & 31;
            *reinterpret_cast<float4*>(&Lp[ss][c * 4]) =
                *reinterpret_cast<const float4*>(
                    P + (size_t)ps[list[s0 + ss]] * DDIM + ihalf * 128 + c * 4);
        }
        __syncthreads();

        bf16x8 bq[8];
#pragma unroll
        for (int kt = 0; kt < 8; ++kt) {
#pragma unroll
            for (int eh = 0; eh < 2; ++eh) {
#pragma unroll
                for (int ev = 0; ev < 4; ++ev) {
                    float v = (s < ns) ? Lq[s][kt * 32 + eh * 16 + kg * 4 + ev]
                                       : 0.f;
                    bq[kt][eh * 4 + ev] = (short)f2bf(v);
                }
            }
        }

        float acc_out = 0.f;
#pragma unroll
        for (int ibl = 0; ibl < 2; ++ibl) {
            const int ibh = w * 2 + ibl;
            const int ibg = ihalf * 8 + ibh;
            // layout: elem = ibg*4096 + row16*256 + kt*32 + kg*8 + e
            const unsigned short* abase =
                Mbase + (size_t)ibg * 4096 + (lane & 15) * 256 + kg * 8;
            bf16x8 af[8];
#pragma unroll
            for (int kt = 0; kt < 8; ++kt)
                af[kt] = *reinterpret_cast<const bf16x8*>(abase + kt * 32);
            f32x4 acc = {0.f, 0.f, 0.f, 0.f};
#pragma unroll
            for (int kt = 0; kt < 8; ++kt)
                acc = __builtin_amdgcn_mfma_f32_16x16x32_bf16(af[kt], bq[kt],
                                                              acc, 0, 0, 0);
#pragma unroll
            for (int reg = 0; reg < 4; ++reg) {
                int il = ibh * 16 + kg * 4 + reg;
                float pv = (s < ns) ? Lp[s][il] : 0.f;
                acc_out += acc[reg] * pv;
            }
        }
        acc_out += __shfl_xor(acc_out, 16, 64);
        acc_out += __shfl_xor(acc_out, 32, 64);
        if (lane < 16) red[s][w] = acc_out;
        __syncthreads();
        if (t < ns)
            partial[(size_t)ihalf * B + list[s0 + t]] =
                red[t][0] + red[t][1] + red[t][2] + red[t][3];
        __syncthreads();
    }
}

// ---------------- final reduce + regularizer --------------------------------
__global__ __launch_bounds__(256)
void sum_out_kernel(const float* __restrict__ partial,
                    const float* __restrict__ norms, float* __restrict__ out,
                    int B) {
    int b = blockIdx.x * 256 + threadIdx.x;
    if (b < B) out[b] = partial[b] + partial[(size_t)B + b];
    if (blockIdx.x == 0 && threadIdx.x == 0)
        out[B] = 0.01f * (sqrtf(norms[0]) + sqrtf(norms[1]) + sqrtf(norms[2]));
}

// ---------------- Launch -----------------------------------------------------
extern "C" void kernel_launch(void* const* d_in, const int* in_sizes, int n_in,
                              void* d_out, int out_size, void* d_ws,
                              size_t ws_size, hipStream_t stream) {
    const int*   ps = (const int*)d_in[0];
    const int*   qs = (const int*)d_in[1];
    const int*   rs = (const int*)d_in[2];
    const float* P  = (const float*)d_in[3];
    const float* Q  = (const float*)d_in[4];
    const float* R  = (const float*)d_in[5];
    const float* W  = (const float*)d_in[6];
    float* out = (float*)d_out;

    const int B      = in_sizes[0];
    const int NUM_RS = in_sizes[5] / DDIM;

    size_t off = 0;
    float* norms = (float*)((char*)d_ws + off);          off += 256;
    int* offs    = (int*)((char*)d_ws + off);            off += (size_t)(NUM_RS + 1) * 4;
    int* list    = (int*)((char*)d_ws + off);            off += (size_t)B * 4;
    off = (off + 255) & ~(size_t)255;
    float* partial = (float*)((char*)d_ws + off);        off += (size_t)NCH2 * B * 4;
    off = (off + 255) & ~(size_t)255;
    unsigned short* Rb = (unsigned short*)((char*)d_ws + off);
    off += (size_t)NUM_RS * DDIM * 2;
    off = (off + 255) & ~(size_t)255;
    unsigned short* Wt = (unsigned short*)((char*)d_ws + off);
    off += (size_t)NIK * DDIM * 2;
    off = (off + 255) & ~(size_t)255;
    unsigned short* WR = (unsigned short*)((char*)d_ws + off);

    size_t wr_bytes = (ws_size > off) ? ws_size - off : 0;
    int max_chunk = (int)(wr_bytes / ((size_t)NIK * 2));
    if (max_chunk > NUM_RS) max_chunk = NUM_RS;
    if (max_chunk < 1) max_chunk = 1;

    fused_csr_kernel<<<1, 1024, 0, stream>>>(rs, offs, list, norms, B, NUM_RS);
    norm_kernel<<<dim3(128, 4), 256, 0, stream>>>(ps, qs, rs, P, Q, R, Rb,
                                                  norms, B, NUM_RS * DDIM / 4);
    conv_wt_kernel<<<dim3(4, 2, DDIM), 256, 0, stream>>>(W, Wt);

    for (int lo = 0; lo < NUM_RS; lo += max_chunk) {
        int cnt = NUM_RS - lo;
        if (cnt > max_chunk) cnt = max_chunk;
        // (64 strips, r-blocks): id = strip + rblk*64 -> XCD = strip%8
        dim3 g1(NIK / BN / NPANEL, (cnt + BM - 1) / BM);
        stage1_kernel<<<g1, 256, 0, stream>>>(Rb, Wt, WR, lo, cnt);
        stage2_kernel<<<dim3(cnt, NCH2), 256, 0, stream>>>(
            list, offs, ps, qs, P, Q, WR, partial, lo, B);
    }
    sum_out_kernel<<<(B + 255) / 256, 256, 0, stream>>>(partial, norms, out, B);
}